// Round 9
// baseline (326.320 us; speedup 1.0000x reference)
//
#include <hip/hip_runtime.h>
#include <math.h>

// ---------------------------------------------------------------------------
// Sinkhorn ETP (FASTopic) on MI355X.
// n=256 topics, m=32768 words, D=384.
//
//   log_K0[i,j] = G[i,j] + su0[i] + sv0[j],  G = 40 * x@y^T
//   Per iteration:  W[j] = log_b - lse_i(G+su);  su'[i] = log_a - lse_j(G+W)
//   Final: transp[i,j] = exp(G+su[i]+W[j]); M = nx[i]+ny[j]-0.05*G;
//          loss = sum(transp*M)
//
// R9-R15: the first-after-gemm G reader pays ~76us (17MB @ ~240GB/s) no
// matter its code/regs/LDS/layout/XCD mapping - a property of the
// gemm->reader boundary (fresh 32MB through non-coherent L2s). Unremovable
// by reader rewrites.
// R16 (WIN, 383->308): persistent sink_loop replaced the 101-launch chain;
// tile register-resident; device-scope generation barrier; convergence
// fused. Anatomy: 76us tile load + ~93us for ~51 iterations (1.8us/iter).
//
// R17: fuse gemm AND finalize into the persistent kernel. G never exists in
// memory: Phase A computes each block's 256x128 tile by MFMA (acc regs ARE
// the tile); Phase B converts fragment->iteration layout via one LDS
// round-trip (4 chunks of 64 rows through pq); Phase C = R16 iterations
// (verbatim); Phase D = fused finalize (transp+loss from regs, nt stores).
// Deletes gemm_k's 32MB store, the 76us boundary read, finalize_k's 32MB
// read, and two dispatches. MFMA = identical 6-term split sequence in
// identical kc order -> G bitwise identical. PIN4 after conversion is
// REQUIRED (conv buffer aliases pq; remat would read overwritten LDS).
// LDS: one 63.5KB union (gemm staging 63.5 ⊔ iter 47). x-staging
// XOR-swizzled (slot ^= row&7) for conflict-free A-fragment reads.
// Predicted: fused_k 130-160us (FETCH ~50MB, WRITE ~34MB), total ~170-210.
// Falsifiers: spill -> restructure conversion; absmax blowup -> mapping bug.
// ---------------------------------------------------------------------------

#define N_TOPIC 256
#define N_WORD  32768

static constexpr float LOG_A = -5.545177444479562f;    // log(1/256 + 1e-30)
static constexpr float LOG_B = -10.397207708399179f;   // log(1/32768 + 1e-30)
static constexpr float BVAL  = 3.0517578125e-05f;      // 1/32768

typedef float f32x4 __attribute__((ext_vector_type(4)));
typedef short bf16x8 __attribute__((ext_vector_type(8)));

#define PIN4(v) asm volatile("" : "+v"((v).x), "+v"((v).y), "+v"((v).z), "+v"((v).w))

// ---------------------------------------------------------------- init ------
__global__ __launch_bounds__(256) void init_k(
    const float* __restrict__ x, const float* __restrict__ y,
    float* __restrict__ nx, float* __restrict__ ny, float* __restrict__ su,
    unsigned* __restrict__ colerr, int* __restrict__ active,
    int* __restrict__ counters, float* __restrict__ out)
{
    const int b = blockIdx.x, t = threadIdx.x;
    const int w = t >> 6, l = t & 63;
    if (b < 8192) {                       // ||y_j||^2, 4 rows/block (wave per row)
        const int r = (b << 2) + w;
        const float4* y4 = (const float4*)y;
        float4 v = y4[r * 96 + l];
        float s = v.x * v.x + v.y * v.y + v.z * v.z + v.w * v.w;
        if (l < 32) {
            float4 u = y4[r * 96 + 64 + l];
            s += u.x * u.x + u.y * u.y + u.z * u.z + u.w * u.w;
        }
        for (int off = 32; off; off >>= 1) s += __shfl_down(s, off);
        if (l == 0) ny[r] = s;
    } else if (b < 8256) {                // ||x_i||^2 and su0 = -20*nx
        const int r = ((b - 8192) << 2) + w;
        const float4* x4 = (const float4*)x;
        float4 v = x4[r * 96 + l];
        float s = v.x * v.x + v.y * v.y + v.z * v.z + v.w * v.w;
        if (l < 32) {
            float4 u = x4[r * 96 + 64 + l];
            s += u.x * u.x + u.y * u.y + u.z * u.z + u.w * u.w;
        }
        for (int off = 32; off; off >>= 1) s += __shfl_down(s, off);
        if (l == 0) { nx[r] = s; su[r] = -20.f * s; }
    } else {
        for (int k = t; k < 4096; k += 256) counters[k] = 0;
        if (t == 0) { colerr[0] = 0u; colerr[1] = 0u; active[0] = 1; out[0] = 0.f; }
    }
}

// Exact 3-way bf16 truncation split: v = b0 + b1 + b2 (+ r3, |r3|<=2^-27|v|).
static __device__ __forceinline__ void split3(float v, ushort& h0, ushort& h1, ushort& h2)
{
    unsigned u0 = __float_as_uint(v);
    h0 = (ushort)(u0 >> 16);
    float r1 = v - __uint_as_float(u0 & 0xFFFF0000u);
    unsigned u1 = __float_as_uint(r1);
    h1 = (ushort)(u1 >> 16);
    float r2 = r1 - __uint_as_float(u1 & 0xFFFF0000u);
    h2 = (ushort)(__float_as_uint(r2) >> 16);
}

// ----------------------------------------------- persistent barrier ---------
static __device__ __forceinline__ bool bar_arrive(int* cnt, int ph, int t, int* lastf)
{
    __threadfence();
    if (t == 0) *lastf = (atomicAdd(&cnt[ph], 1) == 255);
    __syncthreads();
    return *lastf != 0;
}
static __device__ __forceinline__ void bar_release(int* gen, int ph, int t)
{
    __threadfence();
    if (t == 0) atomicExch(gen, ph);
}
static __device__ __forceinline__ void bar_wait(int* gen, int ph, int t)
{
    if (t == 0) {
        while (atomicCAS(gen, -1, -1) < ph) __builtin_amdgcn_s_sleep(2);
    }
    __syncthreads();
    __threadfence();
}

// --------------------------------- fused gemm + Sinkhorn + finalize ---------
// 256 blocks x 256 threads, 1 block/CU. Block b owns cols [128b,128b+128).
// Phase A: MFMA G-tile (256x128) into acc[4][8] (wave w = rows [64w,64w+64)).
// Phase B: acc -> tile[32] (thread t: rows ig+8k, float4-col jq) via LDS.
// Phase C: R16 iterations (verbatim). Phase D: fused finalize.
__global__ __launch_bounds__(256, 1) void fused_k(
    const float* __restrict__ x, const float* __restrict__ y,
    float* __restrict__ su, const float* __restrict__ nx,
    const float* __restrict__ ny, float2* __restrict__ pms,
    float* __restrict__ prow, int* __restrict__ cnt, int* __restrict__ gen,
    unsigned* __restrict__ colerr, int* __restrict__ active,
    float* __restrict__ out)
{
    __shared__ __align__(16) char smem[63488];
    __shared__ int lastf;
    // gemm-phase region
    float4* xs4 = (float4*)smem;                  // [256 rows][8 slots] 32768B
    ushort* ys0 = (ushort*)(smem + 32768);        // [128][40] 10240B
    ushort* ys1 = (ushort*)(smem + 43008);
    ushort* ys2 = (ushort*)(smem + 53248);        // ends 63488
    // iteration/finalize region (alive after Phase A)
    float* su_lds = (float*)smem;                 // 256f
    float* mm    = (float*)(smem + 1024);         // 1024f
    float* ss    = (float*)(smem + 5120);         // 1024f
    float* Mcol  = (float*)(smem + 9216);         // 128f
    float* Wlds  = (float*)(smem + 9728);         // 128f
    float* ecol  = (float*)(smem + 10240);        // 128f
    float* Rlds  = (float*)(smem + 10752);        // 256f
    float* errb  = (float*)(smem + 11776);        // 128f
    float* nxl   = (float*)(smem + 12288);        // 256f
    float* nyl   = (float*)(smem + 13312);        // 128f
    float* pq    = (float*)(smem + 13824);        // 8448f (33792B) ends 47616
    float* cv    = pq;                            // conversion chunk [64][132]

    const int t  = threadIdx.x;
    const int b  = blockIdx.x;
    const int w  = t >> 6, ln = t & 63, q = ln >> 4, l15 = ln & 15;
    const int jq = t & 31, ig = t >> 5, c0 = jq << 2;
    const int jy0 = b << 7;
    int ph = 1;

    const float4* x4 = (const float4*)x;
    const float4* y4 = (const float4*)y;

    // ================= Phase A: G-tile by MFMA =================
    f32x4 acc[4][8];
#pragma unroll
    for (int mi = 0; mi < 4; ++mi)
#pragma unroll
        for (int nj = 0; nj < 8; ++nj) acc[mi][nj] = (f32x4){0.f, 0.f, 0.f, 0.f};

    for (int kc = 0; kc < 12; ++kc) {
        __syncthreads();
        // stage x: 256 rows x 8 float4-slots, XOR-swizzled (slot ^= row&7)
#pragma unroll
        for (int p = 0; p < 8; ++p) {
            const int f = (p << 8) + t;          // 0..2047
            const int r = f >> 3, c4 = f & 7;
            xs4[(r << 3) + (c4 ^ (r & 7))] = x4[r * 96 + (kc << 3) + c4];
        }
        // stage y slab rows [128b,128b+128) with 3-way bf16 split
#pragma unroll
        for (int p = 0; p < 4; ++p) {
            const int f = (p << 8) + t;          // 0..1023
            const int r = f >> 3, c4 = f & 7;
            float4 vy = y4[(size_t)(jy0 + r) * 96 + (kc << 3) + c4];
            ushort a0,a1,a2,b0,b1,b2,g0,g1,g2,d0,d1,d2;
            split3(vy.x, a0,a1,a2); split3(vy.y, b0,b1,b2);
            split3(vy.z, g0,g1,g2); split3(vy.w, d0,d1,d2);
            *(ushort4*)&ys0[r * 40 + (c4 << 2)] = make_ushort4(a0,b0,g0,d0);
            *(ushort4*)&ys1[r * 40 + (c4 << 2)] = make_ushort4(a1,b1,g1,d1);
            *(ushort4*)&ys2[r * 40 + (c4 << 2)] = make_ushort4(a2,b2,g2,d2);
        }
        __syncthreads();

        // A fragments: row = 64w + 16mi + l15, k-offset q*8 (split on the fly)
        union U8 { ushort u[8]; bf16x8 v; };
        bf16x8 A0[4], A1[4], A2[4];
#pragma unroll
        for (int mi = 0; mi < 4; ++mi) {
            const int row = (w << 6) + (mi << 4) + l15;
            const int base = row << 3;
            float4 xa = xs4[base + (((q << 1) + 0) ^ (row & 7))];
            float4 xb = xs4[base + (((q << 1) + 1) ^ (row & 7))];
            U8 u0, u1, u2;
            split3(xa.x, u0.u[0], u1.u[0], u2.u[0]);
            split3(xa.y, u0.u[1], u1.u[1], u2.u[1]);
            split3(xa.z, u0.u[2], u1.u[2], u2.u[2]);
            split3(xa.w, u0.u[3], u1.u[3], u2.u[3]);
            split3(xb.x, u0.u[4], u1.u[4], u2.u[4]);
            split3(xb.y, u0.u[5], u1.u[5], u2.u[5]);
            split3(xb.z, u0.u[6], u1.u[6], u2.u[6]);
            split3(xb.w, u0.u[7], u1.u[7], u2.u[7]);
            A0[mi] = u0.v; A1[mi] = u1.v; A2[mi] = u2.v;
        }
#pragma unroll
        for (int nj = 0; nj < 8; ++nj) {
            const int off = ((nj << 4) + l15) * 40 + (q << 3);
            bf16x8 B0 = *(const bf16x8*)&ys0[off];
            bf16x8 B1 = *(const bf16x8*)&ys1[off];
            bf16x8 B2 = *(const bf16x8*)&ys2[off];
#pragma unroll
            for (int mi = 0; mi < 4; ++mi) {
                f32x4 c = acc[mi][nj];
                c = __builtin_amdgcn_mfma_f32_16x16x32_bf16(A0[mi], B0, c, 0, 0, 0);
                c = __builtin_amdgcn_mfma_f32_16x16x32_bf16(A0[mi], B1, c, 0, 0, 0);
                c = __builtin_amdgcn_mfma_f32_16x16x32_bf16(A1[mi], B0, c, 0, 0, 0);
                c = __builtin_amdgcn_mfma_f32_16x16x32_bf16(A1[mi], B1, c, 0, 0, 0);
                c = __builtin_amdgcn_mfma_f32_16x16x32_bf16(A0[mi], B2, c, 0, 0, 0);
                c = __builtin_amdgcn_mfma_f32_16x16x32_bf16(A2[mi], B0, c, 0, 0, 0);
                acc[mi][nj] = c;
            }
        }
    }

    // ================= Phase B: acc -> tile (4 chunks of 64 rows) =========
    // acc fragment: global row = 64*wave + 16mi + 4q + r, col = 16nj + l15.
    // tile target: thread t holds rows i = ig + 8k, float4-cols 4jq..4jq+3.
    float4 tile[32];
#pragma unroll
    for (int c = 0; c < 4; ++c) {
        __syncthreads();
        if (w == c) {
#pragma unroll
            for (int mi = 0; mi < 4; ++mi) {
                const int rl = (mi << 4) + (q << 2);
#pragma unroll
                for (int nj = 0; nj < 8; ++nj) {
                    const int col = (nj << 4) + l15;
#pragma unroll
                    for (int r = 0; r < 4; ++r)
                        cv[(rl + r) * 132 + col] = 40.f * acc[mi][nj][r];
                }
            }
        }
        __syncthreads();
#pragma unroll
        for (int kk = 0; kk < 8; ++kk) {
            const int il = ig + (kk << 3);
            tile[(c << 3) + kk] = *(const float4*)&cv[il * 132 + c0];
        }
    }
#pragma unroll
    for (int k = 0; k < 32; ++k) PIN4(tile[k]);

    __syncthreads();
    su_lds[t] = su[t];               // su0 = -20*|x|^2
    __syncthreads();

    // ================= Phase C: iterations (R16 verbatim) =================
    // ---- iteration 1 (log-safe, exact lse) ----
    {
        float m0=-INFINITY,m1=-INFINITY,m2=-INFINITY,m3=-INFINITY;
#pragma unroll
        for (int k = 0; k < 32; ++k) {
            const float sk = su_lds[ig + (k << 3)];
            m0=fmaxf(m0,tile[k].x+sk); m1=fmaxf(m1,tile[k].y+sk);
            m2=fmaxf(m2,tile[k].z+sk); m3=fmaxf(m3,tile[k].w+sk);
        }
        float s0=0.f,s1=0.f,s2=0.f,s3=0.f;
#pragma unroll
        for (int k = 0; k < 32; ++k) {
            const float sk = su_lds[ig + (k << 3)];
            s0+=__expf(tile[k].x+sk-m0); s1+=__expf(tile[k].y+sk-m1);
            s2+=__expf(tile[k].z+sk-m2); s3+=__expf(tile[k].w+sk-m3);
        }
        mm[ig*128+c0+0]=m0; ss[ig*128+c0+0]=s0;
        mm[ig*128+c0+1]=m1; ss[ig*128+c0+1]=s1;
        mm[ig*128+c0+2]=m2; ss[ig*128+c0+2]=s2;
        mm[ig*128+c0+3]=m3; ss[ig*128+c0+3]=s3;
        __syncthreads();
        if (t < 128) {
            float m=-INFINITY, s=0.f;
#pragma unroll
            for (int qq = 0; qq < 8; ++qq) {
                float pmv=mm[qq*128+t], psv=ss[qq*128+t];
                float nm=fmaxf(m,pmv);
                s = s*__expf(m-nm) + psv*__expf(pmv-nm);
                m = nm;
            }
            Wlds[t] = LOG_B - (m + __logf(s));
        }
        __syncthreads();
    }
    {
#pragma unroll
        for (int k = 0; k < 32; ++k) {
            const int i = ig + (k << 3);
            float a0=tile[k].x+Wlds[c0], a1=tile[k].y+Wlds[c0+1];
            float a2=tile[k].z+Wlds[c0+2], a3=tile[k].w+Wlds[c0+3];
            pq[i*33+jq] = fmaxf(fmaxf(a0,a1), fmaxf(a2,a3));
        }
        __syncthreads();
        {
            float R=-INFINITY;
#pragma unroll
            for (int qq = 0; qq < 32; ++qq) R = fmaxf(R, pq[t*33+qq]);
            Rlds[t] = R;
        }
        __syncthreads();
#pragma unroll
        for (int k = 0; k < 32; ++k) {
            const int i = ig + (k << 3);
            const float Rr = Rlds[i];
            float s = __expf(tile[k].x+Wlds[c0]-Rr)   + __expf(tile[k].y+Wlds[c0+1]-Rr)
                    + __expf(tile[k].z+Wlds[c0+2]-Rr) + __expf(tile[k].w+Wlds[c0+3]-Rr);
            pq[i*33+jq] = s;
        }
        __syncthreads();
        {
            float s = 0.f;
#pragma unroll
            for (int qq = 0; qq < 32; ++qq) s += pq[t*33+qq];
            pms[(b << 8) + t] = make_float2(Rlds[t], s);
        }
    }
    if (bar_arrive(cnt, ph, t, &lastf)) {
        __threadfence();
        float m=-INFINITY, s=0.f;
        for (int p = 0; p < 256; ++p) {
            float2 v = pms[(p << 8) + t];
            float nm = fmaxf(m, v.x);
            s = s*__expf(m-nm) + v.y*__expf(v.x-nm);
            m = nm;
        }
        su[t] = LOG_A - (m + __logf(s));
        bar_release(gen, ph, t);
    }
    bar_wait(gen, ph, t); ++ph;
    su_lds[t] = su[t];
    __syncthreads();

    // ---- convergence check #1 (ref cpt_n=1) ----
    int act;
    {
        float m0=-INFINITY,m1=-INFINITY,m2=-INFINITY,m3=-INFINITY;
#pragma unroll
        for (int k = 0; k < 32; ++k) {
            const float sk = su_lds[ig + (k << 3)];
            m0=fmaxf(m0,tile[k].x+sk); m1=fmaxf(m1,tile[k].y+sk);
            m2=fmaxf(m2,tile[k].z+sk); m3=fmaxf(m3,tile[k].w+sk);
        }
        float s0=0.f,s1=0.f,s2=0.f,s3=0.f;
#pragma unroll
        for (int k = 0; k < 32; ++k) {
            const float sk = su_lds[ig + (k << 3)];
            s0+=__expf(tile[k].x+sk-m0); s1+=__expf(tile[k].y+sk-m1);
            s2+=__expf(tile[k].z+sk-m2); s3+=__expf(tile[k].w+sk-m3);
        }
        mm[ig*128+c0+0]=m0; ss[ig*128+c0+0]=s0;
        mm[ig*128+c0+1]=m1; ss[ig*128+c0+1]=s1;
        mm[ig*128+c0+2]=m2; ss[ig*128+c0+2]=s2;
        mm[ig*128+c0+3]=m3; ss[ig*128+c0+3]=s3;
        __syncthreads();
        if (t < 128) {
            float m=-INFINITY, s=0.f;
#pragma unroll
            for (int qq = 0; qq < 8; ++qq) {
                float pmv=mm[qq*128+t], psv=ss[qq*128+t];
                float nm=fmaxf(m,pmv);
                s = s*__expf(m-nm) + psv*__expf(pmv-nm);
                m = nm;
            }
            errb[t] = fabsf(__expf((m + __logf(s)) + Wlds[t]) - BVAL);
        }
        __syncthreads();
        for (int n = 64; n; n >>= 1) {
            if (t < n) errb[t] = fmaxf(errb[t], errb[t + n]);
            __syncthreads();
        }
        if (t == 0) atomicMax(&colerr[0], __float_as_uint(errb[0]));
        if (bar_arrive(cnt, ph, t, &lastf)) {
            if (t == 0) {
                unsigned e = atomicMax(&colerr[0], 0u);
                active[0] = (__uint_as_float(e) > 0.005f) ? 1 : 0;
            }
            bar_release(gen, ph, t);
        }
        bar_wait(gen, ph, t); ++ph;
        act = active[0];
    }

    // ---- fast iterations 2..100 (E-reuse) ----
    if (act) {
#pragma unroll 1
        for (int tt = 2; tt <= 100; ++tt) {
            {
                float m0=-INFINITY,m1=-INFINITY,m2=-INFINITY,m3=-INFINITY;
#pragma unroll
                for (int k = 0; k < 32; ++k) {
                    const float sk = su_lds[ig + (k << 3)];
                    m0=fmaxf(m0,tile[k].x+sk); m1=fmaxf(m1,tile[k].y+sk);
                    m2=fmaxf(m2,tile[k].z+sk); m3=fmaxf(m3,tile[k].w+sk);
                }
                mm[ig*128+c0+0]=m0; mm[ig*128+c0+1]=m1;
                mm[ig*128+c0+2]=m2; mm[ig*128+c0+3]=m3;
                __syncthreads();
                if (t < 128) {
                    float m=-INFINITY;
#pragma unroll
                    for (int qq = 0; qq < 8; ++qq) m = fmaxf(m, mm[qq*128+t]);
                    Mcol[t] = m;
                }
                __syncthreads();
            }
            float4 E[32];
            {
                const float Mc0=Mcol[c0], Mc1=Mcol[c0+1], Mc2=Mcol[c0+2], Mc3=Mcol[c0+3];
                float s0=0.f,s1=0.f,s2=0.f,s3=0.f;
#pragma unroll
                for (int k = 0; k < 32; ++k) {
                    const float sk = su_lds[ig + (k << 3)];
                    E[k].x=__expf(tile[k].x+sk-Mc0); s0+=E[k].x;
                    E[k].y=__expf(tile[k].y+sk-Mc1); s1+=E[k].y;
                    E[k].z=__expf(tile[k].z+sk-Mc2); s2+=E[k].z;
                    E[k].w=__expf(tile[k].w+sk-Mc3); s3+=E[k].w;
                }
                ss[ig*128+c0+0]=s0; ss[ig*128+c0+1]=s1;
                ss[ig*128+c0+2]=s2; ss[ig*128+c0+3]=s3;
                __syncthreads();
                if (t < 128) {
                    float ssum = 0.f;
#pragma unroll
                    for (int qq = 0; qq < 8; ++qq) ssum += ss[qq*128+t];
                    Wlds[t] = LOG_B - (Mcol[t] + __logf(ssum));
                    ecol[t] = 1.0f / ssum;
                }
                __syncthreads();
            }
            {
                const float e0=ecol[c0], e1=ecol[c0+1], e2=ecol[c0+2], e3=ecol[c0+3];
#pragma unroll
                for (int k = 0; k < 32; ++k) {
                    const int i = ig + (k << 3);
                    pq[i*33+jq] = E[k].x*e0 + E[k].y*e1 + E[k].z*e2 + E[k].w*e3;
                }
                __syncthreads();
                float s = 0.f;
#pragma unroll
                for (int qq = 0; qq < 32; ++qq) s += pq[t*33+qq];
                prow[(b << 8) + t] = s;
            }
            if (bar_arrive(cnt, ph, t, &lastf)) {
                __threadfence();
                float tot = 0.f;
                for (int p = 0; p < 256; ++p) tot += prow[(p << 8) + t];
                su[t] = (LOG_A - LOG_B) + su_lds[t] - __logf(tot);
                bar_release(gen, ph, t);
            }
            bar_wait(gen, ph, t); ++ph;
            su_lds[t] = su[t];
            __syncthreads();

            if (tt == 51) {
                float m0=-INFINITY,m1=-INFINITY,m2=-INFINITY,m3=-INFINITY;
#pragma unroll
                for (int k = 0; k < 32; ++k) {
                    const float sk = su_lds[ig + (k << 3)];
                    m0=fmaxf(m0,tile[k].x+sk); m1=fmaxf(m1,tile[k].y+sk);
                    m2=fmaxf(m2,tile[k].z+sk); m3=fmaxf(m3,tile[k].w+sk);
                }
                float s0=0.f,s1=0.f,s2=0.f,s3=0.f;
#pragma unroll
                for (int k = 0; k < 32; ++k) {
                    const float sk = su_lds[ig + (k << 3)];
                    s0+=__expf(tile[k].x+sk-m0); s1+=__expf(tile[k].y+sk-m1);
                    s2+=__expf(tile[k].z+sk-m2); s3+=__expf(tile[k].w+sk-m3);
                }
                mm[ig*128+c0+0]=m0; ss[ig*128+c0+0]=s0;
                mm[ig*128+c0+1]=m1; ss[ig*128+c0+1]=s1;
                mm[ig*128+c0+2]=m2; ss[ig*128+c0+2]=s2;
                mm[ig*128+c0+3]=m3; ss[ig*128+c0+3]=s3;
                __syncthreads();
                if (t < 128) {
                    float m=-INFINITY, s=0.f;
#pragma unroll
                    for (int qq = 0; qq < 8; ++qq) {
                        float pmv=mm[qq*128+t], psv=ss[qq*128+t];
                        float nm=fmaxf(m,pmv);
                        s = s*__expf(m-nm) + psv*__expf(pmv-nm);
                        m = nm;
                    }
                    errb[t] = fabsf(__expf((m + __logf(s)) + Wlds[t]) - BVAL);
                }
                __syncthreads();
                for (int n = 64; n; n >>= 1) {
                    if (t < n) errb[t] = fmaxf(errb[t], errb[t + n]);
                    __syncthreads();
                }
                if (t == 0) atomicMax(&colerr[1], __float_as_uint(errb[0]));
                if (bar_arrive(cnt, ph, t, &lastf)) {
                    if (t == 0) {
                        unsigned e = atomicMax(&colerr[1], 0u);
                        active[0] = (__uint_as_float(e) > 0.005f) ? 1 : 0;
                    }
                    bar_release(gen, ph, t);
                }
                bar_wait(gen, ph, t); ++ph;
                if (active[0] == 0) break;
            }
        }
    }

    // ================= Phase D: fused finalize =================
    nxl[t] = nx[t];
    if (t < 128) nyl[t] = ny[jy0 + t];
    __syncthreads();

    float accl = 0.f;
#pragma unroll 4
    for (int k = 0; k < 32; ++k) {
        const int i = ig + (k << 3);
        const float si = su_lds[i], nxi = nxl[i];
        const float g0 = tile[k].x, g1 = tile[k].y, g2 = tile[k].z, g3 = tile[k].w;
        float v0 = __expf(g0 + si + Wlds[c0+0]);
        float v1 = __expf(g1 + si + Wlds[c0+1]);
        float v2 = __expf(g2 + si + Wlds[c0+2]);
        float v3 = __expf(g3 + si + Wlds[c0+3]);
        float* o = out + 1 + (size_t)i * 32768 + jy0 + c0;
        __builtin_nontemporal_store(v0, o + 0);
        __builtin_nontemporal_store(v1, o + 1);
        __builtin_nontemporal_store(v2, o + 2);
        __builtin_nontemporal_store(v3, o + 3);
        accl += v0 * (nxi + nyl[c0+0] - 0.05f * g0) +
                v1 * (nxi + nyl[c0+1] - 0.05f * g1) +
                v2 * (nxi + nyl[c0+2] - 0.05f * g2) +
                v3 * (nxi + nyl[c0+3] - 0.05f * g3);
    }
    for (int off = 32; off; off >>= 1) accl += __shfl_down(accl, off);
    if (ln == 0) errb[w] = accl;
    __syncthreads();
    if (t == 0) atomicAdd(out, errb[0] + errb[1] + errb[2] + errb[3]);
}

// ---------------------------------------------------------------- host ------
extern "C" void kernel_launch(void* const* d_in, const int* in_sizes, int n_in,
                              void* d_out, int out_size, void* d_ws, size_t ws_size,
                              hipStream_t stream)
{
    const float* x = (const float*)d_in[0];   // [256, 384]
    const float* y = (const float*)d_in[1];   // [32768, 384]
    float* out = (float*)d_out;               // [1 + 256*32768]

    float* ws   = (float*)d_ws;
    float* su   = ws;                              // 256
    float* nx   = su + 256;                        // 256
    float* ny   = nx + 256;                        // 32768
    float2* pms = (float2*)(ny + 32768);           // 65536 float2
    float* prow = (float*)(pms + 65536);           // 65536
    unsigned* colerr = (unsigned*)(prow + 65536);  // 2
    int* active   = (int*)(colerr + 2);            // 1
    int* counters = active + 1;                    // 4096 (barrier slots + gen)
    int* gen      = counters + 3000;

    init_k<<<8257, 256, 0, stream>>>(x, y, nx, ny, su, colerr, active, counters, out);
    fused_k<<<256, 256, 0, stream>>>(x, y, su, nx, ny, pms, prow,
                                     counters, gen, colerr, active, out);
}